// Round 9
// baseline (100.449 us; speedup 1.0000x reference)
//
#include <hip/hip_runtime.h>

// Problem constants: B=16 batches, A=5 agents, C=512 channels, H=W=16.
#define NB 16
#define NA 5
#define NC 512
#define HW 256        // 16*16
#define NBLK 2560     // 5120/2560 = exactly 2 items/block (uniform tail);
                      // 2560 = 10 queued/CU against 5 resident (LDS cap)
#define NTOT 5120     // 5*16*64 8-channel items

typedef _Float16 h8 __attribute__((ext_vector_type(8)));   // 16 B = one ds_read_b128

static __device__ __forceinline__ h8 splat8(float v) {
    const _Float16 h = (_Float16)v;
    h8 r = {h, h, h, h, h, h, h, h};
    return r;
}

// Force wave-uniform values into SGPRs (trans entries depend only on block
// indices; scalar regs keep the pair-uniform weight math off the VALU).
static __device__ __forceinline__ float rfl(float v) {
    return __builtin_bit_cast(float,
        __builtin_amdgcn_readfirstlane(__builtin_bit_cast(int, v)));
}

// Measured-best structure (R8: dur 95.0): two-phase pipelined, persistent
// blocks, 3 barriers/item. R9 deltas (occupancy theme, no restructure):
//  - Item.nb stored as fp16 h8[4] (16 VGPR/Item vs 32 f32): the cvt must
//    happen before the LDS write anyway; -32 VGPR across cur+nxt.
//  - __launch_bounds__(256,5): pin 5 blocks/CU (VGPR cap ~102), matching the
//    LDS cap 160KiB/32KiB = 5. Spill tripwire = WRITE_SIZE > 41 MB.
//  - grid 2560: exactly 2 items/block (2048 gave 2.5 -> ragged tail).
struct Item {
    int i, b, c0, n;      // wave-uniform -> SGPR
    bool work;
    h8 nb[4];             // neighbor slabs (this thread's pixel), fp16
    float tr[4][6];       // r00 r01 w03 r10 r11 w13  (uniform, SGPR via rfl)
};

// Issue all global loads for item `idx`; values land later (regs), hidden by
// the previous item's gather phase (cvt to fp16 sinks to after the loads land).
static __device__ __forceinline__ Item prefetch_item(
        const float* __restrict__ feat, const float* __restrict__ trans,
        const int* __restrict__ numa, int idx, int p) {
    Item it;
    const int g = idx & 63;
    const int r = idx >> 6;
    it.i = r % NA;
    it.b = r / NA;
    it.c0 = g << 3;
    it.n = numa[it.b * NA];
    it.work = (it.i < it.n) && (it.n > 1);
    if (it.work) {
#pragma unroll
        for (int jj = 0; jj < 4; ++jj) {
            const int j = jj + (jj >= it.i);
            if (j < it.n) {                    // block-uniform
                const float* tw = trans + (((it.b * NA) + it.i) * NA + j) * 16;
                it.tr[jj][0] = rfl(tw[0]);     // r00
                it.tr[jj][1] = rfl(tw[1]);     // r01
                it.tr[jj][2] = rfl(tw[3]);     // w03 (tx source)
                it.tr[jj][3] = rfl(tw[4]);     // r10
                it.tr[jj][4] = rfl(tw[5]);     // r11
                it.tr[jj][5] = rfl(tw[7]);     // w13 (ty source)
                const float* src = feat + ((j * NB + it.b) * NC + it.c0) * HW + p;
                h8 v;
#pragma unroll
                for (int k = 0; k < 8; ++k) v[k] = (_Float16)src[k * HW];
                it.nb[jj] = v;
            }
        }
    }
    return it;
}

__global__ __launch_bounds__(256, 5) void fafmimo_twophase3_kernel(
    const float* __restrict__ feat,   // [A*B][C][256], feat[a*B+b] = local[b][a]
    const float* __restrict__ trans,  // [B][A][A][4][4]
    const int*   __restrict__ numa,   // [B][A], use [:,0]
    float*       __restrict__ out)    // [A*B][C][256]
{
    __shared__ h8 lds_nb[4][HW];      // 16 KiB  staged neighbor slabs
    __shared__ h8 lds_rot[4][HW];     // 16 KiB  rotated intermediates

    const int p = threadIdx.x;
    const int x = p & 15, y = p >> 4;
    const float fx = (float)x - 7.5f;
    const float fy = (float)y - 7.5f;
    bool dirty = false;               // block-uniform

    int idx = blockIdx.x;
    Item cur = prefetch_item(feat, trans, numa, idx, p);

    while (true) {
        // ---- LDS stage phase for cur ----
        if (cur.work) {
            if (dirty) __syncthreads();       // prior item's LDS readers done
#pragma unroll
            for (int jj = 0; jj < 4; ++jj) {
                const int j = jj + (jj >= cur.i);
                if (j < cur.n) lds_nb[jj][p] = cur.nb[jj];
            }
            __syncthreads();
            dirty = true;
        }

        // ---- prefetch next item (loads overlap phases A/B below) ----
        const int nidx = idx + NBLK;
        const bool more = nidx < NTOT;        // block-uniform
        Item nxt;
        if (more) nxt = prefetch_item(feat, trans, numa, nidx, p);

        // ---- residual loads: issued here (L2-hot), consumed only at store ----
        const float* own = feat + ((cur.i * NB + cur.b) * NC + cur.c0) * HW + p;
        float ownv[8];
#pragma unroll
        for (int k = 0; k < 8; ++k) ownv[k] = own[k * HW];

        float psum[8];
#pragma unroll
        for (int k = 0; k < 8; ++k) psum[k] = 0.0f;

        if (cur.work) {
            // ---- Phase A: rotation bilinear at this thread's pixel ----
#pragma unroll
            for (int jj = 0; jj < 4; ++jj) {
                const int j = jj + (jj >= cur.i);
                if (j < cur.n) {
                    const float r00 = cur.tr[jj][0], r01 = cur.tr[jj][1];
                    const float r10 = cur.tr[jj][3], r11 = cur.tr[jj][4];
                    const float bx = r00 * fx + r01 * fy + 7.5f;
                    const float by = r10 * fx + r11 * fy + 7.5f;
                    const float fbx = floorf(bx), fby = floorf(by);
                    const int ix = (int)fbx, iy = (int)fby;
                    const float wx1 = bx - fbx, wy1 = by - fby;
                    const float mx0 = (ix     >= 0 && ix     < 16) ? 1.0f - wx1 : 0.0f;
                    const float mx1 = (ix + 1 >= 0 && ix + 1 < 16) ? wx1 : 0.0f;
                    const float my0 = (iy     >= 0 && iy     < 16) ? 1.0f - wy1 : 0.0f;
                    const float my1 = (iy + 1 >= 0 && iy + 1 < 16) ? wy1 : 0.0f;
                    const int cx0 = min(max(ix, 0), 15), cx1 = min(max(ix + 1, 0), 15);
                    const int cy0 = min(max(iy, 0), 15), cy1 = min(max(iy + 1, 0), 15);
                    const h8 v00 = lds_nb[jj][cy0 * 16 + cx0];
                    const h8 v01 = lds_nb[jj][cy0 * 16 + cx1];
                    const h8 v10 = lds_nb[jj][cy1 * 16 + cx0];
                    const h8 v11 = lds_nb[jj][cy1 * 16 + cx1];
                    lds_rot[jj][p] =
                          v00 * splat8(mx0 * my0) + v01 * splat8(mx1 * my0)
                        + v10 * splat8(mx0 * my1) + v11 * splat8(mx1 * my1);
                }
            }
            __syncthreads();

            // ---- Phase B: pair-uniform 2x2 translation stencil ----
#pragma unroll
            for (int jj = 0; jj < 4; ++jj) {
                const int j = jj + (jj >= cur.i);
                if (j < cur.n) {
                    // all weights wave-uniform (SGPR) except the border masks
                    const float dx =  0.25f * cur.tr[jj][2];
                    const float dy = -0.25f * cur.tr[jj][5];
                    const float fdx = floorf(dx), fdy = floorf(dy);
                    const float tx1 = dx - fdx, tx0 = 1.0f - tx1;
                    const float ty1 = dy - fdy, ty0 = 1.0f - ty1;
                    const int ox = x + (int)fdx;
                    const int oy = y + (int)fdy;
                    const bool inx0 = (ox     >= 0) && (ox     < 16);
                    const bool inx1 = (ox + 1 >= 0) && (ox + 1 < 16);
                    const bool iny0 = (oy     >= 0) && (oy     < 16);
                    const bool iny1 = (oy + 1 >= 0) && (oy + 1 < 16);
                    const float w00 = (inx0 && iny0) ? tx0 * ty0 : 0.0f;
                    const float w10 = (inx1 && iny0) ? tx1 * ty0 : 0.0f;
                    const float w01 = (inx0 && iny1) ? tx0 * ty1 : 0.0f;
                    const float w11 = (inx1 && iny1) ? tx1 * ty1 : 0.0f;
                    const int cx0 = min(max(ox, 0), 15), cx1 = min(max(ox + 1, 0), 15);
                    const int cy0 = min(max(oy, 0), 15), cy1 = min(max(oy + 1, 0), 15);
                    const h8 t00 = lds_rot[jj][cy0 * 16 + cx0];
                    const h8 t01 = lds_rot[jj][cy0 * 16 + cx1];
                    const h8 t10 = lds_rot[jj][cy1 * 16 + cx0];
                    const h8 t11 = lds_rot[jj][cy1 * 16 + cx1];
                    const h8 s = t00 * splat8(w00) + t01 * splat8(w10)
                               + t10 * splat8(w01) + t11 * splat8(w11);
#pragma unroll
                    for (int k = 0; k < 8; ++k) psum[k] += (float)s[k];  // f32 accum
                }
            }
        }

        float* dst = out + ((cur.i * NB + cur.b) * NC + cur.c0) * HW + p;
#pragma unroll
        for (int k = 0; k < 8; ++k) dst[k * HW] = ownv[k] + psum[k];

        if (!more) break;
        cur = nxt;
        idx = nidx;
    }
}

extern "C" void kernel_launch(void* const* d_in, const int* in_sizes, int n_in,
                              void* d_out, int out_size, void* d_ws, size_t ws_size,
                              hipStream_t stream) {
    const float* feat  = (const float*)d_in[0];
    const float* trans = (const float*)d_in[1];
    const int*   numa  = (const int*)d_in[2];
    float* out = (float*)d_out;

    fafmimo_twophase3_kernel<<<dim3(NBLK), dim3(256), 0, stream>>>(
        feat, trans, numa, out);
}

// Round 10
// 99.510 us; speedup vs baseline: 1.0094x; 1.0094x over previous
//
#include <hip/hip_runtime.h>

// Problem constants: B=16 batches, A=5 agents, C=512 channels, H=W=16.
#define NB 16
#define NA 5
#define NC 512
#define HW 256        // 16*16
#define NBLK 2560     // 5120/2560 = exactly 2 items/block. R8's 2048 gave
                      // blocks 0..1023 three items vs two for the rest (3:2
                      // tail imbalance). SOLE delta vs the R8 95.0us kernel.
#define NTOT 5120     // 5*16*64 8-channel items

typedef _Float16 h8 __attribute__((ext_vector_type(8)));   // 16 B = one ds_read_b128

static __device__ __forceinline__ h8 splat8(float v) {
    const _Float16 h = (_Float16)v;
    h8 r = {h, h, h, h, h, h, h, h};
    return r;
}

// Force wave-uniform values into SGPRs (trans entries depend only on block
// indices; scalar regs keep the pair-uniform weight math off the VALU).
static __device__ __forceinline__ float rfl(float v) {
    return __builtin_bit_cast(float,
        __builtin_amdgcn_readfirstlane(__builtin_bit_cast(int, v)));
}

// Measured-best structure (R8: dur 95.0): two-phase pipelined, persistent
// blocks, 3 barriers/item, residual loads issued at gather-phase start.
// R9 POST-MORTEM (100.4, reverted): fp16-converting nb[] inside prefetch
// anchored the vmcnt wait + cvt chain before the gather phase (killing the
// load/compute overlap), and __launch_bounds__(256,5)'s ~102-VGPR cap invites
// the R2/R5 allocator pathologies. Prefetch values MUST stay untouched f32
// until the consuming stage phase; allocator stays unconstrained.
struct Item {
    int i, b, c0, n;      // wave-uniform -> SGPR
    bool work;
    float nb[4][8];       // neighbor slabs (this thread's pixel), f32 until LDS write
    float tr[4][6];       // r00 r01 w03 r10 r11 w13  (uniform, SGPR via rfl)
};

// Issue all global loads for item `idx`; values land later (regs), hidden by
// the previous item's gather phase.
static __device__ __forceinline__ Item prefetch_item(
        const float* __restrict__ feat, const float* __restrict__ trans,
        const int* __restrict__ numa, int idx, int p) {
    Item it;
    const int g = idx & 63;
    const int r = idx >> 6;
    it.i = r % NA;
    it.b = r / NA;
    it.c0 = g << 3;
    it.n = numa[it.b * NA];
    it.work = (it.i < it.n) && (it.n > 1);
    if (it.work) {
#pragma unroll
        for (int jj = 0; jj < 4; ++jj) {
            const int j = jj + (jj >= it.i);
            if (j < it.n) {                    // block-uniform
                const float* tw = trans + (((it.b * NA) + it.i) * NA + j) * 16;
                it.tr[jj][0] = rfl(tw[0]);     // r00
                it.tr[jj][1] = rfl(tw[1]);     // r01
                it.tr[jj][2] = rfl(tw[3]);     // w03 (tx source)
                it.tr[jj][3] = rfl(tw[4]);     // r10
                it.tr[jj][4] = rfl(tw[5]);     // r11
                it.tr[jj][5] = rfl(tw[7]);     // w13 (ty source)
                const float* src = feat + ((j * NB + it.b) * NC + it.c0) * HW + p;
#pragma unroll
                for (int k = 0; k < 8; ++k) it.nb[jj][k] = src[k * HW];
            }
        }
    }
    return it;
}

__global__ __launch_bounds__(256) void fafmimo_twophase4_kernel(
    const float* __restrict__ feat,   // [A*B][C][256], feat[a*B+b] = local[b][a]
    const float* __restrict__ trans,  // [B][A][A][4][4]
    const int*   __restrict__ numa,   // [B][A], use [:,0]
    float*       __restrict__ out)    // [A*B][C][256]
{
    __shared__ h8 lds_nb[4][HW];      // 16 KiB  staged neighbor slabs
    __shared__ h8 lds_rot[4][HW];     // 16 KiB  rotated intermediates

    const int p = threadIdx.x;
    const int x = p & 15, y = p >> 4;
    const float fx = (float)x - 7.5f;
    const float fy = (float)y - 7.5f;
    bool dirty = false;               // block-uniform

    int idx = blockIdx.x;
    Item cur = prefetch_item(feat, trans, numa, idx, p);

    while (true) {
        // ---- LDS stage phase for cur ----
        if (cur.work) {
            if (dirty) __syncthreads();       // prior item's LDS readers done
#pragma unroll
            for (int jj = 0; jj < 4; ++jj) {
                const int j = jj + (jj >= cur.i);
                if (j < cur.n) {
                    h8 v;
#pragma unroll
                    for (int k = 0; k < 8; ++k) v[k] = (_Float16)cur.nb[jj][k];
                    lds_nb[jj][p] = v;
                }
            }
            __syncthreads();
            dirty = true;
        }

        // ---- prefetch next item (loads overlap phases A/B below) ----
        const int nidx = idx + NBLK;
        const bool more = nidx < NTOT;        // block-uniform
        Item nxt;
        if (more) nxt = prefetch_item(feat, trans, numa, nidx, p);

        // ---- residual loads: issued here (L2-hot), consumed only at store ----
        const float* own = feat + ((cur.i * NB + cur.b) * NC + cur.c0) * HW + p;
        float ownv[8];
#pragma unroll
        for (int k = 0; k < 8; ++k) ownv[k] = own[k * HW];

        float psum[8];
#pragma unroll
        for (int k = 0; k < 8; ++k) psum[k] = 0.0f;

        if (cur.work) {
            // ---- Phase A: rotation bilinear at this thread's pixel ----
#pragma unroll
            for (int jj = 0; jj < 4; ++jj) {
                const int j = jj + (jj >= cur.i);
                if (j < cur.n) {
                    const float r00 = cur.tr[jj][0], r01 = cur.tr[jj][1];
                    const float r10 = cur.tr[jj][3], r11 = cur.tr[jj][4];
                    const float bx = r00 * fx + r01 * fy + 7.5f;
                    const float by = r10 * fx + r11 * fy + 7.5f;
                    const float fbx = floorf(bx), fby = floorf(by);
                    const int ix = (int)fbx, iy = (int)fby;
                    const float wx1 = bx - fbx, wy1 = by - fby;
                    const float mx0 = (ix     >= 0 && ix     < 16) ? 1.0f - wx1 : 0.0f;
                    const float mx1 = (ix + 1 >= 0 && ix + 1 < 16) ? wx1 : 0.0f;
                    const float my0 = (iy     >= 0 && iy     < 16) ? 1.0f - wy1 : 0.0f;
                    const float my1 = (iy + 1 >= 0 && iy + 1 < 16) ? wy1 : 0.0f;
                    const int cx0 = min(max(ix, 0), 15), cx1 = min(max(ix + 1, 0), 15);
                    const int cy0 = min(max(iy, 0), 15), cy1 = min(max(iy + 1, 0), 15);
                    const h8 v00 = lds_nb[jj][cy0 * 16 + cx0];
                    const h8 v01 = lds_nb[jj][cy0 * 16 + cx1];
                    const h8 v10 = lds_nb[jj][cy1 * 16 + cx0];
                    const h8 v11 = lds_nb[jj][cy1 * 16 + cx1];
                    lds_rot[jj][p] =
                          v00 * splat8(mx0 * my0) + v01 * splat8(mx1 * my0)
                        + v10 * splat8(mx0 * my1) + v11 * splat8(mx1 * my1);
                }
            }
            __syncthreads();

            // ---- Phase B: pair-uniform 2x2 translation stencil ----
#pragma unroll
            for (int jj = 0; jj < 4; ++jj) {
                const int j = jj + (jj >= cur.i);
                if (j < cur.n) {
                    // all weights wave-uniform (SGPR) except the border masks
                    const float dx =  0.25f * cur.tr[jj][2];
                    const float dy = -0.25f * cur.tr[jj][5];
                    const float fdx = floorf(dx), fdy = floorf(dy);
                    const float tx1 = dx - fdx, tx0 = 1.0f - tx1;
                    const float ty1 = dy - fdy, ty0 = 1.0f - ty1;
                    const int ox = x + (int)fdx;
                    const int oy = y + (int)fdy;
                    const bool inx0 = (ox     >= 0) && (ox     < 16);
                    const bool inx1 = (ox + 1 >= 0) && (ox + 1 < 16);
                    const bool iny0 = (oy     >= 0) && (oy     < 16);
                    const bool iny1 = (oy + 1 >= 0) && (oy + 1 < 16);
                    const float w00 = (inx0 && iny0) ? tx0 * ty0 : 0.0f;
                    const float w10 = (inx1 && iny0) ? tx1 * ty0 : 0.0f;
                    const float w01 = (inx0 && iny1) ? tx0 * ty1 : 0.0f;
                    const float w11 = (inx1 && iny1) ? tx1 * ty1 : 0.0f;
                    const int cx0 = min(max(ox, 0), 15), cx1 = min(max(ox + 1, 0), 15);
                    const int cy0 = min(max(oy, 0), 15), cy1 = min(max(oy + 1, 0), 15);
                    const h8 t00 = lds_rot[jj][cy0 * 16 + cx0];
                    const h8 t01 = lds_rot[jj][cy0 * 16 + cx1];
                    const h8 t10 = lds_rot[jj][cy1 * 16 + cx0];
                    const h8 t11 = lds_rot[jj][cy1 * 16 + cx1];
                    const h8 s = t00 * splat8(w00) + t01 * splat8(w10)
                               + t10 * splat8(w01) + t11 * splat8(w11);
#pragma unroll
                    for (int k = 0; k < 8; ++k) psum[k] += (float)s[k];  // f32 accum
                }
            }
        }

        float* dst = out + ((cur.i * NB + cur.b) * NC + cur.c0) * HW + p;
#pragma unroll
        for (int k = 0; k < 8; ++k) dst[k * HW] = ownv[k] + psum[k];

        if (!more) break;
        cur = nxt;
        idx = nidx;
    }
}

extern "C" void kernel_launch(void* const* d_in, const int* in_sizes, int n_in,
                              void* d_out, int out_size, void* d_ws, size_t ws_size,
                              hipStream_t stream) {
    const float* feat  = (const float*)d_in[0];
    const float* trans = (const float*)d_in[1];
    const int*   numa  = (const int*)d_in[2];
    float* out = (float*)d_out;

    fafmimo_twophase4_kernel<<<dim3(NBLK), dim3(256), 0, stream>>>(
        feat, trans, numa, out);
}

// Round 11
// 97.154 us; speedup vs baseline: 1.0339x; 1.0243x over previous
//
#include <hip/hip_runtime.h>

// FINAL: byte-exact restore of the round-8 champion (dur_us 95.0, session best).
// Ledger: two-phase@2048 = 95.0/96.8; two-phase@2560 = 99.5/100.4 (tail-evening
// disproven); fp16-prefetch + launch_bounds(256,5) = 100.4 (R9, overlap killed);
// all restructures 102.9-178.6 (R2 remat, R5 spill, R6 imbalance, R7 fused
// fine-grain, XOR swizzle conflicts UP). Prefetch values stay untouched f32
// until the stage phase; allocator unconstrained; grid 2048 persistent blocks.
// Problem constants: B=16 batches, A=5 agents, C=512 channels, H=W=16.
#define NB 16
#define NA 5
#define NC 512
#define HW 256        // 16*16
#define NBLK 2048     // measured-best grid; items via stride
#define NTOT 5120     // 5*16*64 8-channel items

typedef _Float16 h8 __attribute__((ext_vector_type(8)));   // 16 B = one ds_read_b128

static __device__ __forceinline__ h8 splat8(float v) {
    const _Float16 h = (_Float16)v;
    h8 r = {h, h, h, h, h, h, h, h};
    return r;
}

// Force wave-uniform values into SGPRs (trans entries depend only on block
// indices; scalar regs keep the pair-uniform weight math off the VALU).
static __device__ __forceinline__ float rfl(float v) {
    return __builtin_bit_cast(float,
        __builtin_amdgcn_readfirstlane(__builtin_bit_cast(int, v)));
}

struct Item {
    int i, b, c0, n;      // wave-uniform -> SGPR
    bool work;
    float nb[4][8];       // neighbor slabs (this thread's pixel), f32 until LDS write
    float tr[4][6];       // r00 r01 w03 r10 r11 w13  (uniform, SGPR via rfl)
};

// Issue all global loads for item `idx`; values land later (regs), hidden by
// the previous item's gather phase.
static __device__ __forceinline__ Item prefetch_item(
        const float* __restrict__ feat, const float* __restrict__ trans,
        const int* __restrict__ numa, int idx, int p) {
    Item it;
    const int g = idx & 63;
    const int r = idx >> 6;
    it.i = r % NA;
    it.b = r / NA;
    it.c0 = g << 3;
    it.n = numa[it.b * NA];
    it.work = (it.i < it.n) && (it.n > 1);
    if (it.work) {
#pragma unroll
        for (int jj = 0; jj < 4; ++jj) {
            const int j = jj + (jj >= it.i);
            if (j < it.n) {                    // block-uniform
                const float* tw = trans + (((it.b * NA) + it.i) * NA + j) * 16;
                it.tr[jj][0] = rfl(tw[0]);     // r00
                it.tr[jj][1] = rfl(tw[1]);     // r01
                it.tr[jj][2] = rfl(tw[3]);     // w03 (tx source)
                it.tr[jj][3] = rfl(tw[4]);     // r10
                it.tr[jj][4] = rfl(tw[5]);     // r11
                it.tr[jj][5] = rfl(tw[7]);     // w13 (ty source)
                const float* src = feat + ((j * NB + it.b) * NC + it.c0) * HW + p;
#pragma unroll
                for (int k = 0; k < 8; ++k) it.nb[jj][k] = src[k * HW];
            }
        }
    }
    return it;
}

__global__ __launch_bounds__(256) void fafmimo_twophase2_kernel(
    const float* __restrict__ feat,   // [A*B][C][256], feat[a*B+b] = local[b][a]
    const float* __restrict__ trans,  // [B][A][A][4][4]
    const int*   __restrict__ numa,   // [B][A], use [:,0]
    float*       __restrict__ out)    // [A*B][C][256]
{
    __shared__ h8 lds_nb[4][HW];      // 16 KiB  staged neighbor slabs
    __shared__ h8 lds_rot[4][HW];     // 16 KiB  rotated intermediates

    const int p = threadIdx.x;
    const int x = p & 15, y = p >> 4;
    const float fx = (float)x - 7.5f;
    const float fy = (float)y - 7.5f;
    bool dirty = false;               // block-uniform

    int idx = blockIdx.x;
    Item cur = prefetch_item(feat, trans, numa, idx, p);

    while (true) {
        // ---- LDS stage phase for cur ----
        if (cur.work) {
            if (dirty) __syncthreads();       // prior item's LDS readers done
#pragma unroll
            for (int jj = 0; jj < 4; ++jj) {
                const int j = jj + (jj >= cur.i);
                if (j < cur.n) {
                    h8 v;
#pragma unroll
                    for (int k = 0; k < 8; ++k) v[k] = (_Float16)cur.nb[jj][k];
                    lds_nb[jj][p] = v;
                }
            }
            __syncthreads();
            dirty = true;
        }

        // ---- prefetch next item (loads overlap phases A/B below) ----
        const int nidx = idx + NBLK;
        const bool more = nidx < NTOT;        // block-uniform
        Item nxt;
        if (more) nxt = prefetch_item(feat, trans, numa, nidx, p);

        // ---- residual loads: issued here (L2-hot), consumed only at store ----
        const float* own = feat + ((cur.i * NB + cur.b) * NC + cur.c0) * HW + p;
        float ownv[8];
#pragma unroll
        for (int k = 0; k < 8; ++k) ownv[k] = own[k * HW];

        float psum[8];
#pragma unroll
        for (int k = 0; k < 8; ++k) psum[k] = 0.0f;

        if (cur.work) {
            // ---- Phase A: rotation bilinear at this thread's pixel ----
#pragma unroll
            for (int jj = 0; jj < 4; ++jj) {
                const int j = jj + (jj >= cur.i);
                if (j < cur.n) {
                    const float r00 = cur.tr[jj][0], r01 = cur.tr[jj][1];
                    const float r10 = cur.tr[jj][3], r11 = cur.tr[jj][4];
                    const float bx = r00 * fx + r01 * fy + 7.5f;
                    const float by = r10 * fx + r11 * fy + 7.5f;
                    const float fbx = floorf(bx), fby = floorf(by);
                    const int ix = (int)fbx, iy = (int)fby;
                    const float wx1 = bx - fbx, wy1 = by - fby;
                    const float mx0 = (ix     >= 0 && ix     < 16) ? 1.0f - wx1 : 0.0f;
                    const float mx1 = (ix + 1 >= 0 && ix + 1 < 16) ? wx1 : 0.0f;
                    const float my0 = (iy     >= 0 && iy     < 16) ? 1.0f - wy1 : 0.0f;
                    const float my1 = (iy + 1 >= 0 && iy + 1 < 16) ? wy1 : 0.0f;
                    const int cx0 = min(max(ix, 0), 15), cx1 = min(max(ix + 1, 0), 15);
                    const int cy0 = min(max(iy, 0), 15), cy1 = min(max(iy + 1, 0), 15);
                    const h8 v00 = lds_nb[jj][cy0 * 16 + cx0];
                    const h8 v01 = lds_nb[jj][cy0 * 16 + cx1];
                    const h8 v10 = lds_nb[jj][cy1 * 16 + cx0];
                    const h8 v11 = lds_nb[jj][cy1 * 16 + cx1];
                    lds_rot[jj][p] =
                          v00 * splat8(mx0 * my0) + v01 * splat8(mx1 * my0)
                        + v10 * splat8(mx0 * my1) + v11 * splat8(mx1 * my1);
                }
            }
            __syncthreads();

            // ---- Phase B: pair-uniform 2x2 translation stencil ----
#pragma unroll
            for (int jj = 0; jj < 4; ++jj) {
                const int j = jj + (jj >= cur.i);
                if (j < cur.n) {
                    // all weights wave-uniform (SGPR) except the border masks
                    const float dx =  0.25f * cur.tr[jj][2];
                    const float dy = -0.25f * cur.tr[jj][5];
                    const float fdx = floorf(dx), fdy = floorf(dy);
                    const float tx1 = dx - fdx, tx0 = 1.0f - tx1;
                    const float ty1 = dy - fdy, ty0 = 1.0f - ty1;
                    const int ox = x + (int)fdx;
                    const int oy = y + (int)fdy;
                    const bool inx0 = (ox     >= 0) && (ox     < 16);
                    const bool inx1 = (ox + 1 >= 0) && (ox + 1 < 16);
                    const bool iny0 = (oy     >= 0) && (oy     < 16);
                    const bool iny1 = (oy + 1 >= 0) && (oy + 1 < 16);
                    const float w00 = (inx0 && iny0) ? tx0 * ty0 : 0.0f;
                    const float w10 = (inx1 && iny0) ? tx1 * ty0 : 0.0f;
                    const float w01 = (inx0 && iny1) ? tx0 * ty1 : 0.0f;
                    const float w11 = (inx1 && iny1) ? tx1 * ty1 : 0.0f;
                    const int cx0 = min(max(ox, 0), 15), cx1 = min(max(ox + 1, 0), 15);
                    const int cy0 = min(max(oy, 0), 15), cy1 = min(max(oy + 1, 0), 15);
                    const h8 t00 = lds_rot[jj][cy0 * 16 + cx0];
                    const h8 t01 = lds_rot[jj][cy0 * 16 + cx1];
                    const h8 t10 = lds_rot[jj][cy1 * 16 + cx0];
                    const h8 t11 = lds_rot[jj][cy1 * 16 + cx1];
                    const h8 s = t00 * splat8(w00) + t01 * splat8(w10)
                               + t10 * splat8(w01) + t11 * splat8(w11);
#pragma unroll
                    for (int k = 0; k < 8; ++k) psum[k] += (float)s[k];  // f32 accum
                }
            }
        }

        float* dst = out + ((cur.i * NB + cur.b) * NC + cur.c0) * HW + p;
#pragma unroll
        for (int k = 0; k < 8; ++k) dst[k * HW] = ownv[k] + psum[k];

        if (!more) break;
        cur = nxt;
        idx = nidx;
    }
}

extern "C" void kernel_launch(void* const* d_in, const int* in_sizes, int n_in,
                              void* d_out, int out_size, void* d_ws, size_t ws_size,
                              hipStream_t stream) {
    const float* feat  = (const float*)d_in[0];
    const float* trans = (const float*)d_in[1];
    const int*   numa  = (const int*)d_in[2];
    float* out = (float*)d_out;

    fafmimo_twophase2_kernel<<<dim3(NBLK), dim3(256), 0, stream>>>(
        feat, trans, numa, out);
}